// Round 3
// baseline (322.200 us; speedup 1.0000x reference)
//
#include <hip/hip_runtime.h>

#define NN 200000
#define DD 256
#define KK 20
#define CHUNK 200            // rows per block
#define NB (NN / CHUNK)      // 1000 blocks, exact

// ---------------------------------------------------------------------------
// K1: streaming pass. Grid = NB x 256 threads (4 waves).
// Block b: rows [b*CHUNK, (b+1)*CHUNK). P slice (CHUNK x KK = 16 KB) staged
// into LDS once; main loop reads P via broadcast ds_read_b128 (conflict-free,
// short latency). Wave w handles local rows 4i+w; its 64 lanes cover the full
// 256-col row via float4 (lane -> cols 4*lane..4*lane+3). acc[KK][4]/lane.
// Z is explicitly software-pipelined (3 float4 buffers, prefetch distance 2);
// only 12 VGPRs of pipeline state, so launch_bounds(256,3) leaves slack
// (~168-reg cap for ~120 used) -> 12 waves/CU, 24 KB/CU of Z in flight.
// ---------------------------------------------------------------------------

#define SLOAD(i, zv) zv = Zr[(size_t)((((i) << 2) + w) * 64 + lane)];

#define SCOMP(i, zv)                                                        \
  {                                                                         \
    const float4* pr_ = (const float4*)(smem + ((((i) << 2) + w) * KK));    \
    float4 p0_ = pr_[0], p1_ = pr_[1], p2_ = pr_[2], p3_ = pr_[3],          \
           p4_ = pr_[4];                                                    \
    float zz_[4] = {zv.x, zv.y, zv.z, zv.w};                                \
    float pv_[KK] = {p0_.x, p0_.y, p0_.z, p0_.w, p1_.x, p1_.y, p1_.z,       \
                     p1_.w, p2_.x, p2_.y, p2_.z, p2_.w, p3_.x, p3_.y,       \
                     p3_.z, p3_.w, p4_.x, p4_.y, p4_.z, p4_.w};             \
    t1 += zz_[0] * zz_[0] + zz_[1] * zz_[1];                                \
    t1 += zz_[2] * zz_[2] + zz_[3] * zz_[3];                                \
    _Pragma("unroll") for (int k_ = 0; k_ < KK; ++k_) {                     \
      _Pragma("unroll") for (int c_ = 0; c_ < 4; ++c_)                      \
          acc[k_][c_] += zz_[c_] * pv_[k_];                                 \
    }                                                                       \
  }

__global__ __launch_bounds__(256, 3) void egac_main(
    const float* __restrict__ Z, const float* __restrict__ P,
    float* __restrict__ ztp_part, float* __restrict__ t1_part) {
  const int t = threadIdx.x;
  const int lane = t & 63;
  const int w = t >> 6;  // wave id 0..3 (wave-uniform)
  const int b = blockIdx.x;
  const int base = b * CHUNK;

  // 20480 B: holds P slice (CHUNK*KK = 4000 floats) during the main loop,
  // then reused as the [KK][DD] cross-wave reduction buffer.
  __shared__ float smem[KK * DD];
  __shared__ float wsum[4];

  // ---- stage P slice into LDS (coalesced float4) ----
  {
    const float4* Psrc = (const float4*)(P + (size_t)base * KK);
    float4* pl4 = (float4*)smem;
    const int n4 = CHUNK * KK / 4;  // 1000
#pragma unroll
    for (int i = 0; i < 4; ++i) {
      int idx = t + i * 256;
      if (idx < n4) pl4[idx] = Psrc[idx];
    }
  }
  __syncthreads();

  float acc[KK][4];
#pragma unroll
  for (int k = 0; k < KK; ++k)
#pragma unroll
    for (int c = 0; c < 4; ++c) acc[k][c] = 0.f;
  float t1 = 0.f;

  const float4* Zr = (const float4*)(Z + (size_t)base * DD);
  const int nit = CHUNK / 4;  // 50 stages per wave

  float4 zA, zB, zC;
  SLOAD(0, zA);
  SLOAD(1, zB);

  int s = 0;
  const int m_end = (nit - 2) / 3;  // 16
  for (int m = 0; m < m_end; ++m) {
    SLOAD(s + 2, zC);
    SCOMP(s, zA);
    SLOAD(s + 3, zA);
    SCOMP(s + 1, zB);
    SLOAD(s + 4, zB);
    SCOMP(s + 2, zC);
    s += 3;
  }
  // generic rotating tail (<= 4 iterations; handles (nit-2) % 3 != 0 too)
  for (int i = s; i < nit; ++i) {
    if (i + 2 < nit) SLOAD(i + 2, zC);
    SCOMP(i, zA);
    zA = zB;
    zB = zC;
  }

  // ---- intra-block reduction over the 4 waves (smem reused) ----
  __syncthreads();  // all waves done reading the P slice
  float(*red)[DD] = (float(*)[DD])smem;
  for (int ph = 0; ph < 4; ++ph) {
    if (w == ph) {
      if (ph == 0) {
#pragma unroll
        for (int k = 0; k < KK; ++k)
          ((float4*)&red[k][0])[lane] =
              make_float4(acc[k][0], acc[k][1], acc[k][2], acc[k][3]);
      } else {
#pragma unroll
        for (int k = 0; k < KK; ++k) {
          float4 r = ((float4*)&red[k][0])[lane];
          r.x += acc[k][0];
          r.y += acc[k][1];
          r.z += acc[k][2];
          r.w += acc[k][3];
          ((float4*)&red[k][0])[lane] = r;
        }
      }
    }
    __syncthreads();
  }

  // term1: per-wave shuffle reduce, 4 wave leaders -> LDS
#pragma unroll
  for (int off = 32; off > 0; off >>= 1) t1 += __shfl_xor(t1, off, 64);
  if (lane == 0) wsum[w] = t1;
  __syncthreads();

  // coalesced float4 write-out of the 5120-float block partial
  float4* dst = (float4*)(ztp_part + (size_t)b * (KK * DD));
  const float4* src = (const float4*)&red[0][0];
#pragma unroll
  for (int i = 0; i < (KK * DD) / (4 * 256); ++i)
    dst[i * 256 + t] = src[i * 256 + t];
  if (t == 0) t1_part[b] = wsum[0] + wsum[1] + wsum[2] + wsum[3];
}

// ---------------------------------------------------------------------------
// K2: cross-block reduction + final scalar. Grid = 160 blocks x 512 threads.
// Block handles 32 entries of the 5120-entry ztp; thread = (psub = t>>5,
// e_local = t&31); thread sums partials p = psub, psub+16, ..., LDS tree over
// 16 psubs, square-sum -> one atomicAdd per block. Block 0 folds in term1.
// ---------------------------------------------------------------------------
__global__ __launch_bounds__(512) void egac_reduce(
    const float* __restrict__ ztp_part, const float* __restrict__ t1_part,
    float* __restrict__ out, int nb) {
  __shared__ float red[16][32];
  const int t = threadIdx.x;
  const int el = t & 31;
  const int ps = t >> 5;  // 0..15
  const int e = blockIdx.x * 32 + el;

  float s = 0.f;
  for (int p = ps; p < nb; p += 16) s += ztp_part[(size_t)p * (KK * DD) + e];
  red[ps][el] = s;
  __syncthreads();
  for (int sh = 8; sh >= 1; sh >>= 1) {
    if (ps < sh) red[ps][el] += red[ps + sh][el];
    __syncthreads();
  }
  if (t == 0) {
    float ssq = 0.f;
#pragma unroll
    for (int i = 0; i < 32; ++i) {
      float v = red[0][i];
      ssq += v * v;
    }
    atomicAdd(out, -ssq);  // term2 enters negatively
  }

  if (blockIdx.x == 0) {
    float v = 0.f;
    for (int i = t; i < nb; i += 512) v += t1_part[i];
#pragma unroll
    for (int off = 32; off > 0; off >>= 1) v += __shfl_xor(v, off, 64);
    __shared__ float w2[8];
    if ((t & 63) == 0) w2[t >> 6] = v;
    __syncthreads();
    if (t == 0) {
      float tt = 0.f;
#pragma unroll
      for (int i = 0; i < 8; ++i) tt += w2[i];
      atomicAdd(out, tt);  // + term1
    }
  }
}

extern "C" void kernel_launch(void* const* d_in, const int* in_sizes, int n_in,
                              void* d_out, int out_size, void* d_ws,
                              size_t ws_size, hipStream_t stream) {
  const float* Z = (const float*)d_in[0];
  const float* P = (const float*)d_in[1];
  float* out = (float*)d_out;

  // ws: NB * 5120 floats of ztp partials + NB floats of term1 partials
  // (~20.5 MB; R1/R2 confirmed ws_size is far larger).
  float* ztp_part = (float*)d_ws;
  float* t1_part = (float*)d_ws + (size_t)NB * KK * DD;

  hipMemsetAsync(d_out, 0, sizeof(float), stream);
  egac_main<<<NB, 256, 0, stream>>>(Z, P, ztp_part, t1_part);
  egac_reduce<<<160, 512, 0, stream>>>(ztp_part, t1_part, out, NB);
}